// Round 9
// baseline (31.487 us; speedup 1.0000x reference)
//
#include <hip/hip_runtime.h>
#include <math.h>
#include <float.h>

#define NS 8
#define NA 64
#define NP 32
#define NT 80
#define NK 6
#define NAG (NS*NA)           // 512 agents
#define PAIRS 496             // 32*31/2

// out layout offsets (floats)
#define BASE1 ((size_t)NS*NT*NA*NK*2)          // yaw after xy
#define BASE2 (BASE1 + (size_t)NS*NT*NA*NK)    // spd
#define BASE3 (BASE2 + (size_t)NS*NT*NA*NK)    // scores
#define BASE4 (BASE3 + (size_t)NS*NA*NK)       // valid
#define G1 (NS*NT*NA*NK)                       // 245760 traj elems
#define G2 (NS*NT*NA)                          // 40960 valid elems

// ============ kA: ADE + MTR NMS + MPA NMS + softmax (no output copy) ============
__global__ __launch_bounds__(512) void kA_nms(
    const void* __restrict__ valid_raw,
    const float* __restrict__ scores,
    const float* __restrict__ trajs,
    const float* __restrict__ atype,
    int* __restrict__ ws_sel, float* __restrict__ ws_vld,
    float* __restrict__ out_scores)
{
    const int bid = blockIdx.x;
    const int blk = (bid & 7) * 64 + (bid >> 3);   // XCD-aware agent swizzle
    const int tid = threadIdx.x;

    __shared__ float2 sxy[NT][NP + 1];   // 21120 B  xy only
    __shared__ float sade[NP][NP];       // 4096 B full ADE matrix
    __shared__ unsigned wloc[NP];        // MTR within rows (incl diagonal)

    if (tid < NP) wloc[tid] = 1u << tid;

    // early prefetch of tail inputs
    unsigned u0 = 0, u1 = 0; float sc = 0.0f;
    if (tid < 64) {
        const unsigned* vw = (const unsigned*)valid_raw;
        u0 = vw[tid]; u1 = vw[tid + 64];
        sc = scores[blk*NP + (tid & 31)];
    }
    const float a0 = atype[blk*3+0], a1 = atype[blk*3+1], a2 = atype[blk*3+2];
    const float thrM = a0*3.5f + a1*1.0f + a2*1.75f;
    const float thrQ = a0*2.5f + a1*1.0f + a2*1.5f;

    // ---- phase A: stage xy (read full float4 lines, keep xy) ----
    const float4* tg4 = (const float4*)trajs + (size_t)blk * NP * NT;
    #pragma unroll
    for (int rep = 0; rep < 5; ++rep) {
        int l = tid + rep*512;           // 2560 records
        int p = l / NT, t = l - p*NT;
        float4 v = tg4[l];
        sxy[t][p] = make_float2(v.x, v.y);
    }
    __syncthreads();

    // ---- phase B: 2x2 register-tiled pairs, 4 t-slices (unchanged from R8) ----
    {
        const int tile = tid >> 2, slice = tid & 3;
        int A_, B_, C_, D_;
        bool offd = (tile < 120);
        if (offd) {
            float fs = sqrtf((float)(1 + 8*tile));
            int tj = (int)((1.0f + fs) * 0.5f);
            int ti = tile - ((tj*(tj-1)) >> 1);
            A_ = 2*ti; B_ = 2*ti+1; C_ = 2*tj; D_ = 2*tj+1;
        } else {
            int m = tile - 120;
            A_ = 4*m; B_ = 4*m+2; C_ = 4*m+1; D_ = 4*m+3;
        }
        float accAC = 0.0f, accAD = 0.0f, accBC = 0.0f, accBD = 0.0f;
        const int tbase = slice * 20;
        #pragma unroll 4
        for (int tt = 0; tt < 20; ++tt) {
            int t = tbase + tt;
            float2 va = sxy[t][A_], vb = sxy[t][B_];
            float2 vc = sxy[t][C_], vd = sxy[t][D_];
            float dx, dy;
            dx = va.x - vc.x; dy = va.y - vc.y; accAC += sqrtf(fmaf(dx,dx,dy*dy));
            dx = va.x - vd.x; dy = va.y - vd.y; accAD += sqrtf(fmaf(dx,dx,dy*dy));
            dx = vb.x - vc.x; dy = vb.y - vc.y; accBC += sqrtf(fmaf(dx,dx,dy*dy));
            dx = vb.x - vd.x; dy = vb.y - vd.y; accBD += sqrtf(fmaf(dx,dx,dy*dy));
        }
        const int qb = (tid & 63) & ~3;
#define FOLD(acc) ((((acc) + __shfl((acc), qb+1)) + __shfl((acc), qb+2)) + __shfl((acc), qb+3))
        float fAC = FOLD(accAC);
        float fAD = FOLD(accAD);
        float fBC = FOLD(accBC);
        float fBD = FOLD(accBD);
#undef FOLD
        if (slice == 0) {
            const float inv = 1.0f / (float)NT;
            float e0 = fAC*inv, e1 = fAD*inv, e2 = fBC*inv, e3 = fBD*inv;
            sade[A_][C_] = e0; sade[C_][A_] = e0;
            if (e0 < thrM) { atomicOr(&wloc[A_], 1u<<C_); atomicOr(&wloc[C_], 1u<<A_); }
            sade[B_][D_] = e3; sade[D_][B_] = e3;
            if (e3 < thrM) { atomicOr(&wloc[B_], 1u<<D_); atomicOr(&wloc[D_], 1u<<B_); }
            if (offd) {
                sade[A_][D_] = e1; sade[D_][A_] = e1;
                if (e1 < thrM) { atomicOr(&wloc[A_], 1u<<D_); atomicOr(&wloc[D_], 1u<<A_); }
                sade[B_][C_] = e2; sade[C_][B_] = e2;
                if (e2 < thrM) { atomicOr(&wloc[B_], 1u<<C_); atomicOr(&wloc[C_], 1u<<B_); }
            }
        }
    }
    __syncthreads();

    // ---- phase C: NMS pipeline on wave 0 ----
    if (tid < 64) {
        const int lane = tid;
        const int p = lane & 31;

        // valid[] encoding detection (u8 bool / i32 / f32)
        bool fHit = (u0 == 0x3F800000u) || (u1 == 0x3F800000u);
        int nz0 = ((u0&0xFFu)!=0)+((u0&0xFF00u)!=0)+((u0&0xFF0000u)!=0)+((u0&0xFF000000u)!=0);
        int nz1 = ((u1&0xFFu)!=0)+((u1&0xFF00u)!=0)+((u1&0xFF0000u)!=0)+((u1&0xFF000000u)!=0);
        bool isF = __any(fHit), multi = __any(nz0 >= 2 || nz1 >= 2);
        int vflag;
        if (isF)        vflag = (((const float*)valid_raw)[blk] != 0.0f);
        else if (multi) vflag = (((const unsigned char*)valid_raw)[blk] != 0);
        else            vflag = (((const int*)valid_raw)[blk] != 0);

        unsigned wl = wloc[p];

        // greedy MTR scan: 5-level fmax reduce + ballot/ffs argmax
        // (jnp.argmax first-index tie-break == lowest set lane in ballot)
        float carry = sc;
        int sel_0, sel_1, sel_2, sel_3, sel_4, sel_5;
#define GREEDY(SK) { \
        float vv = carry; \
        _Pragma("unroll") \
        for (int off = 16; off; off >>= 1) vv = fmaxf(vv, __shfl_xor(vv, off)); \
        unsigned long long mba = __ballot(carry == vv); \
        int bi = __ffsll((long long)mba) - 1; \
        SK = bi; \
        unsigned rbi = __shfl(wl, bi); \
        carry = (p == bi) ? -1.0f : (((rbi >> p) & 1u) ? carry*0.01f : carry); }
        GREEDY(sel_0) GREEDY(sel_1) GREEDY(sel_2) GREEDY(sel_3) GREEDY(sel_4) GREEDY(sel_5)
#undef GREEDY

        float q0 = __shfl(sc, sel_0), q1 = __shfl(sc, sel_1), q2 = __shfl(sc, sel_2);
        float q3 = __shfl(sc, sel_3), q4 = __shfl(sc, sel_4), q5 = __shfl(sc, sel_5);

        // MPA 6x6 within from LDS ADE matrix (lanes 0-14, one pair each)
        int ii = (lane<5)?0 : (lane<9)?1 : (lane<12)?2 : (lane<14)?3 : 4;
        int jj = lane - ((ii==0)?-1 : (ii==1)?3 : (ii==2)?6 : (ii==3)?8 : 9);
        jj = (jj < 0) ? 0 : (jj > 5 ? 5 : jj);
        int pi = (ii==0)?sel_0:(ii==1)?sel_1:(ii==2)?sel_2:(ii==3)?sel_3:(ii==4)?sel_4:sel_5;
        int pj = (jj==0)?sel_0:(jj==1)?sel_1:(jj==2)?sel_2:(jj==3)?sel_3:(jj==4)?sel_4:sel_5;
        float ade15 = sade[pi][pj];
        bool within = (lane < 15) && (ade15 < thrQ);
        unsigned long long bal = __ballot(within);
#define B(i) ((unsigned)((bal >> (i)) & 1ull))
        unsigned w6_0 = (B(0)<<1)|(B(1)<<2)|(B(2)<<3)|(B(3)<<4)|(B(4)<<5);
        unsigned w6_1 = (B(0)<<0)|(B(5)<<2)|(B(6)<<3)|(B(7)<<4)|(B(8)<<5);
        unsigned w6_2 = (B(1)<<0)|(B(5)<<1)|(B(9)<<3)|(B(10)<<4)|(B(11)<<5);
        unsigned w6_3 = (B(2)<<0)|(B(6)<<1)|(B(9)<<2)|(B(12)<<4)|(B(13)<<5);
        unsigned w6_4 = (B(3)<<0)|(B(7)<<1)|(B(10)<<2)|(B(12)<<3)|(B(14)<<5);
        unsigned w6_5 = (B(4)<<0)|(B(8)<<1)|(B(11)<<2)|(B(13)<<3)|(B(14)<<4);
#undef B

        // stable ranks (argsort(-q), ties -> lower index)
#define GE(x,y) ((x) >= (y))
        bool a01=GE(q0,q1), a02=GE(q0,q2), a03=GE(q0,q3), a04=GE(q0,q4), a05=GE(q0,q5);
        bool a12=GE(q1,q2), a13=GE(q1,q3), a14=GE(q1,q4), a15=GE(q1,q5);
        bool a23=GE(q2,q3), a24=GE(q2,q4), a25=GE(q2,q5);
        bool a34=GE(q3,q4), a35=GE(q3,q5);
        bool a45=GE(q4,q5);
#undef GE
        int r0 = (!a01)+(!a02)+(!a03)+(!a04)+(!a05);
        int r1 = a01+(!a12)+(!a13)+(!a14)+(!a15);
        int r2 = a02+a12+(!a23)+(!a24)+(!a25);
        int r3 = a03+a13+a23+(!a34)+(!a35);
        int r4 = a04+a14+a24+a34+(!a45);
        int r5 = a05+a15+a25+a35+a45;

        // serial MPA scan, exact semantics, all-scalar
        const float sum6 = q0+q1+q2+q3+q4+q5;
        const float supv = 0.001f * sum6;
#define STEP(m) { \
        float ck = (r0==m)?q0:(r1==m)?q1:(r2==m)?q2:(r3==m)?q3:(r4==m)?q4:q5; \
        unsigned wk = (r0==m)?w6_0:(r1==m)?w6_1:(r2==m)?w6_2:(r3==m)?w6_3:(r4==m)?w6_4:w6_5; \
        bool sup = (((wk>>0)&1u)&&(q0>ck))||(((wk>>1)&1u)&&(q1>ck))||(((wk>>2)&1u)&&(q2>ck)) \
                 ||(((wk>>3)&1u)&&(q3>ck))||(((wk>>4)&1u)&&(q4>ck))||(((wk>>5)&1u)&&(q5>ck)); \
        bool go = vflag && sup; \
        q0 = (go&&(r0==m))?supv:q0; q1 = (go&&(r1==m))?supv:q1; q2 = (go&&(r2==m))?supv:q2; \
        q3 = (go&&(r3==m))?supv:q3; q4 = (go&&(r4==m))?supv:q4; q5 = (go&&(r5==m))?supv:q5; }
        STEP(0) STEP(1) STEP(2) STEP(3) STEP(4) STEP(5)
#undef STEP

        // softmax(1.25*ln q) — shift/scale-invariant reduction of reference
        float g0 = logf(q0)*1.25f, g1 = logf(q1)*1.25f, g2 = logf(q2)*1.25f;
        float g3 = logf(q3)*1.25f, g4 = logf(q4)*1.25f, g5 = logf(q5)*1.25f;
        float mx = fmaxf(fmaxf(fmaxf(g0,g1),fmaxf(g2,g3)),fmaxf(g4,g5));
        float e0 = expf(g0-mx), e1 = expf(g1-mx), e2 = expf(g2-mx);
        float e3 = expf(g3-mx), e4 = expf(g4-mx), e5 = expf(g5-mx);
        float es = e0+e1+e2+e3+e4+e5;

        if (lane < NK) {
            float fv = (lane==0)?e0:(lane==1)?e1:(lane==2)?e2:(lane==3)?e3:(lane==4)?e4:e5;
            int   sv = (lane==0)?sel_0:(lane==1)?sel_1:(lane==2)?sel_2:(lane==3)?sel_3:(lane==4)?sel_4:sel_5;
            out_scores[blk*NK + lane] = fv / es;
            ws_sel[blk*8 + lane] = sv;
        }
        if (lane == 0) ws_vld[blk] = vflag ? 1.0f : 0.0f;
    }
}

// ================= kB: coalesced transposed output copy (R2-proven) =================
__global__ __launch_bounds__(256) void kB_copy(
    const float* __restrict__ trajs, const int* __restrict__ ws_sel,
    const float* __restrict__ ws_vld, float* __restrict__ out)
{
    int g = blockIdx.x * 256 + threadIdx.x;
    if (g < G1) {
        int k = g % NK; int r = g / NK;
        int a = r % NA;  r /= NA;
        int t = r % NT;  int s = r / NT;
        int agent = s*NA + a;
        int sl = ws_sel[agent*8 + k];
        const float4* tg = (const float4*)trajs;
        float4 vv = tg[((size_t)agent*NP + sl)*NT + t];
        ((float2*)out)[g] = make_float2(vv.x, vv.y);   // xy coalesced
        out[BASE1 + g] = vv.z;                          // yaw coalesced
        out[BASE2 + g] = vv.w;                          // spd coalesced
    } else if (g < G1 + G2) {
        int g2 = g - G1;                                // (s,t,a)
        int a = g2 % NA; int st = g2 / NA;
        int s = st / NT;
        out[BASE4 + g2] = ws_vld[s*NA + a];
    }
}

extern "C" void kernel_launch(void* const* d_in, const int* in_sizes, int n_in,
                              void* d_out, int out_size, void* d_ws, size_t ws_size,
                              hipStream_t stream) {
    const void*  valid  = d_in[0];
    const float* scores = (const float*)d_in[1];
    const float* trajs  = (const float*)d_in[2];
    const float* atype  = (const float*)d_in[3];
    float* out = (float*)d_out;

    int*   ws_sel = (int*)d_ws;                          // 512*8 ints
    float* ws_vld = (float*)((char*)d_ws + NAG*8*4);     // 512 floats

    kA_nms<<<NAG, 512, 0, stream>>>(valid, scores, trajs, atype,
                                    ws_sel, ws_vld, out + BASE3);
    kB_copy<<<(G1 + G2 + 255)/256, 256, 0, stream>>>(trajs, ws_sel, ws_vld, out);
}

// Round 10
// 19.581 us; speedup vs baseline: 1.6081x; 1.6081x over previous
//
#include <hip/hip_runtime.h>
#include <math.h>
#include <float.h>

#define NS 8
#define NA 64
#define NP 32
#define NT 80
#define NK 6
#define NAG (NS*NA)           // 512 agents
#define PAIRS 496             // 32*31/2

// fast single-instruction sqrt (v_sqrt_f32, ~1 ULP; plain -O3 sqrtf expands to
// a correctly-rounded multi-instr sequence -- 40k sqrts/agent make that the
// dominant VALU cost)
#define FSQRT(x) __builtin_amdgcn_sqrtf(x)

// out layout offsets (floats)
#define BASE1 ((size_t)NS*NT*NA*NK*2)          // yaw after xy
#define BASE2 (BASE1 + (size_t)NS*NT*NA*NK)    // spd
#define BASE3 (BASE2 + (size_t)NS*NT*NA*NK)    // scores
#define BASE4 (BASE3 + (size_t)NS*NA*NK)       // valid

// ============ fully fused: ADE + MTR NMS + MPA NMS + softmax + write ============
// 512 threads/block (8 waves) -> 2 blocks/CU = 4 waves/SIMD.
__global__ __launch_bounds__(512) void k_fused(
    const void* __restrict__ valid_raw,
    const float* __restrict__ scores,
    const float* __restrict__ trajs,
    const float* __restrict__ atype,
    float* __restrict__ out)
{
    const int bid = blockIdx.x;
    const int blk = (bid & 7) * 64 + (bid >> 3);   // XCD-aware agent swizzle
    const int s = blk >> 6;
    const int a = blk & 63;
    const int tid = threadIdx.x;

    __shared__ float2 sxy[NT][NP + 1];   // 21120 B  xy
    __shared__ float2 szw[NT][NP + 1];   // 21120 B  yaw/spd
    __shared__ float sade[NP][NP];       // 4096 B full ADE matrix
    __shared__ unsigned wloc[NP];        // MTR within rows (incl diagonal)
    __shared__ int   sel6[NK];
    __shared__ float fsc6[NK];
    __shared__ float vf_sh;

    if (tid < NP) wloc[tid] = 1u << tid;

    // ---- early prefetch of tail inputs (hide HBM latency under staging) ----
    unsigned u0 = 0, u1 = 0; float sc = 0.0f;
    if (tid < 64) {
        const unsigned* vw = (const unsigned*)valid_raw;
        u0 = vw[tid]; u1 = vw[tid + 64];
        sc = scores[blk*NP + (tid & 31)];
    }
    const float a0 = atype[blk*3+0], a1 = atype[blk*3+1], a2 = atype[blk*3+2];
    const float thrM = a0*3.5f + a1*1.0f + a2*1.75f;
    const float thrQ = a0*2.5f + a1*1.0f + a2*1.5f;

    // ---- phase A: stage full float4 records, coalesced 1KB/wave ----
    const float4* tg4 = (const float4*)trajs + (size_t)blk * NP * NT;
    #pragma unroll
    for (int rep = 0; rep < 5; ++rep) {
        int l = tid + rep*512;           // 2560 records
        int p = l / NT, t = l - p*NT;
        float4 v = tg4[l];
        sxy[t][p] = make_float2(v.x, v.y);
        szw[t][p] = make_float2(v.z, v.w);
    }
    __syncthreads();

    // ---- phase B: 2x2 register-tiled pairs, 4 t-slices (1 LDS op per pair-t) ----
    {
        const int tile = tid >> 2, slice = tid & 3;
        int A_, B_, C_, D_;
        bool offd = (tile < 120);
        if (offd) {
            // library sqrtf here: must be exact on perfect squares (once/thread)
            float fs = sqrtf((float)(1 + 8*tile));
            int tj = (int)((1.0f + fs) * 0.5f);
            int ti = tile - ((tj*(tj-1)) >> 1);
            A_ = 2*ti; B_ = 2*ti+1; C_ = 2*tj; D_ = 2*tj+1;
        } else {
            int m = tile - 120;
            A_ = 4*m; B_ = 4*m+2; C_ = 4*m+1; D_ = 4*m+3;
        }
        float accAC = 0.0f, accAD = 0.0f, accBC = 0.0f, accBD = 0.0f;
        const int tbase = slice * 20;
        #pragma unroll 4
        for (int tt = 0; tt < 20; ++tt) {
            int t = tbase + tt;
            float2 va = sxy[t][A_], vb = sxy[t][B_];
            float2 vc = sxy[t][C_], vd = sxy[t][D_];
            float dx, dy;
            dx = va.x - vc.x; dy = va.y - vc.y; accAC += FSQRT(fmaf(dx,dx,dy*dy));
            dx = va.x - vd.x; dy = va.y - vd.y; accAD += FSQRT(fmaf(dx,dx,dy*dy));
            dx = vb.x - vc.x; dy = vb.y - vc.y; accBC += FSQRT(fmaf(dx,dx,dy*dy));
            dx = vb.x - vd.x; dy = vb.y - vd.y; accBD += FSQRT(fmaf(dx,dx,dy*dy));
        }
        const int qb = (tid & 63) & ~3;
#define FOLD(acc) ((((acc) + __shfl((acc), qb+1)) + __shfl((acc), qb+2)) + __shfl((acc), qb+3))
        float fAC = FOLD(accAC);
        float fAD = FOLD(accAD);
        float fBC = FOLD(accBC);
        float fBD = FOLD(accBD);
#undef FOLD
        if (slice == 0) {
            const float inv = 1.0f / (float)NT;
            float e0 = fAC*inv, e1 = fAD*inv, e2 = fBC*inv, e3 = fBD*inv;
            sade[A_][C_] = e0; sade[C_][A_] = e0;
            if (e0 < thrM) { atomicOr(&wloc[A_], 1u<<C_); atomicOr(&wloc[C_], 1u<<A_); }
            sade[B_][D_] = e3; sade[D_][B_] = e3;
            if (e3 < thrM) { atomicOr(&wloc[B_], 1u<<D_); atomicOr(&wloc[D_], 1u<<B_); }
            if (offd) {
                sade[A_][D_] = e1; sade[D_][A_] = e1;
                if (e1 < thrM) { atomicOr(&wloc[A_], 1u<<D_); atomicOr(&wloc[D_], 1u<<A_); }
                sade[B_][C_] = e2; sade[C_][B_] = e2;
                if (e2 < thrM) { atomicOr(&wloc[B_], 1u<<C_); atomicOr(&wloc[C_], 1u<<B_); }
            }
        }
    }
    __syncthreads();

    // ---- phase C: NMS pipeline on wave 0 ----
    if (tid < 64) {
        const int lane = tid;
        const int p = lane & 31;

        // valid[] encoding detection (u8 bool / i32 / f32) from prefetched words
        bool fHit = (u0 == 0x3F800000u) || (u1 == 0x3F800000u);
        int nz0 = ((u0&0xFFu)!=0)+((u0&0xFF00u)!=0)+((u0&0xFF0000u)!=0)+((u0&0xFF000000u)!=0);
        int nz1 = ((u1&0xFFu)!=0)+((u1&0xFF00u)!=0)+((u1&0xFF0000u)!=0)+((u1&0xFF000000u)!=0);
        bool isF = __any(fHit), multi = __any(nz0 >= 2 || nz1 >= 2);
        int vflag;
        if (isF)        vflag = (((const float*)valid_raw)[blk] != 0.0f);
        else if (multi) vflag = (((const unsigned char*)valid_raw)[blk] != 0);
        else            vflag = (((const int*)valid_raw)[blk] != 0);

        unsigned wl = wloc[p];

        // greedy MTR scan on raw scores (argmax is scale-invariant)
        float carry = sc;
        int sel_0, sel_1, sel_2, sel_3, sel_4, sel_5;
#define GREEDY(SK) { \
        float vv = carry; int bi = p; \
        _Pragma("unroll") \
        for (int off = 16; off; off >>= 1) { \
            float ov = __shfl_xor(vv, off); \
            int   oi = __shfl_xor(bi, off); \
            if (ov > vv || (ov == vv && oi < bi)) { vv = ov; bi = oi; } \
        } \
        SK = bi; \
        unsigned rbi = __shfl(wl, bi); \
        carry = (p == bi) ? -1.0f : (((rbi >> p) & 1u) ? carry*0.01f : carry); }
        GREEDY(sel_0) GREEDY(sel_1) GREEDY(sel_2) GREEDY(sel_3) GREEDY(sel_4) GREEDY(sel_5)
#undef GREEDY

        float q0 = __shfl(sc, sel_0), q1 = __shfl(sc, sel_1), q2 = __shfl(sc, sel_2);
        float q3 = __shfl(sc, sel_3), q4 = __shfl(sc, sel_4), q5 = __shfl(sc, sel_5);

        // MPA 6x6 within from LDS ADE matrix (lanes 0-14, one pair each)
        int ii = (lane<5)?0 : (lane<9)?1 : (lane<12)?2 : (lane<14)?3 : 4;
        int jj = lane - ((ii==0)?-1 : (ii==1)?3 : (ii==2)?6 : (ii==3)?8 : 9);
        jj = (jj < 0) ? 0 : (jj > 5 ? 5 : jj);
        int pi = (ii==0)?sel_0:(ii==1)?sel_1:(ii==2)?sel_2:(ii==3)?sel_3:(ii==4)?sel_4:sel_5;
        int pj = (jj==0)?sel_0:(jj==1)?sel_1:(jj==2)?sel_2:(jj==3)?sel_3:(jj==4)?sel_4:sel_5;
        float ade15 = sade[pi][pj];
        bool within = (lane < 15) && (ade15 < thrQ);
        unsigned long long bal = __ballot(within);
#define B(i) ((unsigned)((bal >> (i)) & 1ull))
        unsigned w6_0 = (B(0)<<1)|(B(1)<<2)|(B(2)<<3)|(B(3)<<4)|(B(4)<<5);
        unsigned w6_1 = (B(0)<<0)|(B(5)<<2)|(B(6)<<3)|(B(7)<<4)|(B(8)<<5);
        unsigned w6_2 = (B(1)<<0)|(B(5)<<1)|(B(9)<<3)|(B(10)<<4)|(B(11)<<5);
        unsigned w6_3 = (B(2)<<0)|(B(6)<<1)|(B(9)<<2)|(B(12)<<4)|(B(13)<<5);
        unsigned w6_4 = (B(3)<<0)|(B(7)<<1)|(B(10)<<2)|(B(12)<<3)|(B(14)<<5);
        unsigned w6_5 = (B(4)<<0)|(B(8)<<1)|(B(11)<<2)|(B(13)<<3)|(B(14)<<4);
#undef B

        // stable ranks (argsort(-q), ties -> lower index)
#define GE(x,y) ((x) >= (y))
        bool a01=GE(q0,q1), a02=GE(q0,q2), a03=GE(q0,q3), a04=GE(q0,q4), a05=GE(q0,q5);
        bool a12=GE(q1,q2), a13=GE(q1,q3), a14=GE(q1,q4), a15=GE(q1,q5);
        bool a23=GE(q2,q3), a24=GE(q2,q4), a25=GE(q2,q5);
        bool a34=GE(q3,q4), a35=GE(q3,q5);
        bool a45=GE(q4,q5);
#undef GE
        int r0 = (!a01)+(!a02)+(!a03)+(!a04)+(!a05);
        int r1 = a01+(!a12)+(!a13)+(!a14)+(!a15);
        int r2 = a02+a12+(!a23)+(!a24)+(!a25);
        int r3 = a03+a13+a23+(!a34)+(!a35);
        int r4 = a04+a14+a24+a34+(!a45);
        int r5 = a05+a15+a25+a35+a45;

        // serial MPA scan, exact semantics, all-scalar
        const float sum6 = q0+q1+q2+q3+q4+q5;
        const float supv = 0.001f * sum6;
#define STEP(m) { \
        float ck = (r0==m)?q0:(r1==m)?q1:(r2==m)?q2:(r3==m)?q3:(r4==m)?q4:q5; \
        unsigned wk = (r0==m)?w6_0:(r1==m)?w6_1:(r2==m)?w6_2:(r3==m)?w6_3:(r4==m)?w6_4:w6_5; \
        bool sup = (((wk>>0)&1u)&&(q0>ck))||(((wk>>1)&1u)&&(q1>ck))||(((wk>>2)&1u)&&(q2>ck)) \
                 ||(((wk>>3)&1u)&&(q3>ck))||(((wk>>4)&1u)&&(q4>ck))||(((wk>>5)&1u)&&(q5>ck)); \
        bool go = vflag && sup; \
        q0 = (go&&(r0==m))?supv:q0; q1 = (go&&(r1==m))?supv:q1; q2 = (go&&(r2==m))?supv:q2; \
        q3 = (go&&(r3==m))?supv:q3; q4 = (go&&(r4==m))?supv:q4; q5 = (go&&(r5==m))?supv:q5; }
        STEP(0) STEP(1) STEP(2) STEP(3) STEP(4) STEP(5)
#undef STEP

        // softmax(1.25*ln q) via fast log/exp (outputs have 1.82 absmax margin)
        float g0 = __logf(q0)*1.25f, g1 = __logf(q1)*1.25f, g2 = __logf(q2)*1.25f;
        float g3 = __logf(q3)*1.25f, g4 = __logf(q4)*1.25f, g5 = __logf(q5)*1.25f;
        float mx = fmaxf(fmaxf(fmaxf(g0,g1),fmaxf(g2,g3)),fmaxf(g4,g5));
        float e0 = __expf(g0-mx), e1 = __expf(g1-mx), e2 = __expf(g2-mx);
        float e3 = __expf(g3-mx), e4 = __expf(g4-mx), e5 = __expf(g5-mx);
        float es = e0+e1+e2+e3+e4+e5;

        if (lane < NK) {
            float fv = (lane==0)?e0:(lane==1)?e1:(lane==2)?e2:(lane==3)?e3:(lane==4)?e4:e5;
            int   sv = (lane==0)?sel_0:(lane==1)?sel_1:(lane==2)?sel_2:(lane==3)?sel_3:(lane==4)?sel_4:sel_5;
            fsc6[lane] = fv / es;
            sel6[lane] = sv;
        }
        if (lane == 0) vf_sh = vflag ? 1.0f : 0.0f;
    }
    __syncthreads();

    // ---- phase D: vectorized outputs from LDS; thread = (t, k-pair) ----
    if (tid < 3*NT) {
        int t = tid / 3, kp = tid - t*3;
        int k0 = kp*2;
        int s0 = sel6[k0], s1 = sel6[k0+1];
        float2 xy0 = sxy[t][s0], xy1 = sxy[t][s1];
        float2 zw0 = szw[t][s0], zw1 = szw[t][s1];
        size_t ob = (((size_t)(s*NT + t)*NA + a)*NK + k0);   // float2-unit index (even)
        *(float4*)((float2*)out + ob) = make_float4(xy0.x, xy0.y, xy1.x, xy1.y);
        *(float2*)(out + BASE1 + ob) = make_float2(zw0.x, zw1.x);
        *(float2*)(out + BASE2 + ob) = make_float2(zw0.y, zw1.y);
    }
    if (tid < NK) out[BASE3 + (size_t)blk*NK + tid] = fsc6[tid];
    if (tid < NT)
        out[BASE4 + (size_t)(s*NT + tid)*NA + a] = vf_sh;
}

extern "C" void kernel_launch(void* const* d_in, const int* in_sizes, int n_in,
                              void* d_out, int out_size, void* d_ws, size_t ws_size,
                              hipStream_t stream) {
    const void*  valid  = d_in[0];
    const float* scores = (const float*)d_in[1];
    const float* trajs  = (const float*)d_in[2];
    const float* atype  = (const float*)d_in[3];
    k_fused<<<NAG, 512, 0, stream>>>(valid, scores, trajs, atype, (float*)d_out);
}

// Round 11
// 18.973 us; speedup vs baseline: 1.6596x; 1.0320x over previous
//
#include <hip/hip_runtime.h>
#include <math.h>
#include <float.h>

#define NS 8
#define NA 64
#define NP 32
#define NT 80
#define NK 6
#define NAG (NS*NA)           // 512 agents
#define PAIRS 496             // 32*31/2

// single-instruction v_sqrt_f32 (~1 ULP): ADE feeds comparisons with wide margins
#define FSQRT(x) __builtin_amdgcn_sqrtf(x)

// out layout offsets (floats)
#define BASE1 ((size_t)NS*NT*NA*NK*2)          // yaw after xy
#define BASE2 (BASE1 + (size_t)NS*NT*NA*NK)    // spd
#define BASE3 (BASE2 + (size_t)NS*NT*NA*NK)    // scores
#define BASE4 (BASE3 + (size_t)NS*NA*NK)       // valid

// ============ fully fused: ADE + MTR NMS + MPA NMS + softmax + write ============
// 512 threads/block (8 waves) -> 2 blocks/CU = 4 waves/SIMD.
__global__ __launch_bounds__(512) void k_fused(
    const void* __restrict__ valid_raw,
    const float* __restrict__ scores,
    const float* __restrict__ trajs,
    const float* __restrict__ atype,
    float* __restrict__ out)
{
    const int bid = blockIdx.x;
    const int blk = (bid & 7) * 64 + (bid >> 3);   // XCD-aware agent swizzle
    const int s = blk >> 6;
    const int a = blk & 63;
    const int tid = threadIdx.x;
    const int lane = tid & 63;
    const int p = lane & 31;

    __shared__ float2 sxy[NT][NP + 1];   // 21120 B  xy only
    __shared__ float sade[NP][NP];       // 4096 B full ADE matrix
    __shared__ unsigned wloc[NP];        // MTR within rows (incl diagonal)

    if (tid < NP) wloc[tid] = 1u << tid;

    // ---- prefetch tail inputs for EVERY wave (phase C runs per-wave) ----
    const unsigned* vw = (const unsigned*)valid_raw;
    unsigned u0 = vw[lane], u1 = vw[lane + 64];
    float sc = scores[blk*NP + p];
    const float a0 = atype[blk*3+0], a1 = atype[blk*3+1], a2 = atype[blk*3+2];
    const float thrM = a0*3.5f + a1*1.0f + a2*1.75f;
    const float thrQ = a0*2.5f + a1*1.0f + a2*1.5f;

    // ---- phase A: stage xy (read full float4 lines, coalesced) ----
    const float4* tg4 = (const float4*)trajs + (size_t)blk * NP * NT;
    #pragma unroll
    for (int rep = 0; rep < 5; ++rep) {
        int l = tid + rep*512;           // 2560 records
        int pp = l / NT, t = l - pp*NT;
        float4 v = tg4[l];
        sxy[t][pp] = make_float2(v.x, v.y);
    }
    __syncthreads();

    // ---- phase B: 2x2 register-tiled pairs, 4 t-slices ----
    {
        const int tile = tid >> 2, slice = tid & 3;
        int A_, B_, C_, D_;
        bool offd = (tile < 120);
        if (offd) {
            // library sqrtf: must be exact on perfect squares (once/thread)
            float fs = sqrtf((float)(1 + 8*tile));
            int tj = (int)((1.0f + fs) * 0.5f);
            int ti = tile - ((tj*(tj-1)) >> 1);
            A_ = 2*ti; B_ = 2*ti+1; C_ = 2*tj; D_ = 2*tj+1;
        } else {
            int m = tile - 120;
            A_ = 4*m; B_ = 4*m+2; C_ = 4*m+1; D_ = 4*m+3;
        }
        float accAC = 0.0f, accAD = 0.0f, accBC = 0.0f, accBD = 0.0f;
        const int tbase = slice * 20;
        #pragma unroll 4
        for (int tt = 0; tt < 20; ++tt) {
            int t = tbase + tt;
            float2 va = sxy[t][A_], vb = sxy[t][B_];
            float2 vc = sxy[t][C_], vd = sxy[t][D_];
            float dx, dy;
            dx = va.x - vc.x; dy = va.y - vc.y; accAC += FSQRT(fmaf(dx,dx,dy*dy));
            dx = va.x - vd.x; dy = va.y - vd.y; accAD += FSQRT(fmaf(dx,dx,dy*dy));
            dx = vb.x - vc.x; dy = vb.y - vc.y; accBC += FSQRT(fmaf(dx,dx,dy*dy));
            dx = vb.x - vd.x; dy = vb.y - vd.y; accBD += FSQRT(fmaf(dx,dx,dy*dy));
        }
        const int qb = lane & ~3;
#define FOLD(acc) ((((acc) + __shfl((acc), qb+1)) + __shfl((acc), qb+2)) + __shfl((acc), qb+3))
        float fAC = FOLD(accAC);
        float fAD = FOLD(accAD);
        float fBC = FOLD(accBC);
        float fBD = FOLD(accBD);
#undef FOLD
        if (slice == 0) {
            const float inv = 1.0f / (float)NT;
            float e0 = fAC*inv, e1 = fAD*inv, e2 = fBC*inv, e3 = fBD*inv;
            sade[A_][C_] = e0; sade[C_][A_] = e0;
            if (e0 < thrM) { atomicOr(&wloc[A_], 1u<<C_); atomicOr(&wloc[C_], 1u<<A_); }
            sade[B_][D_] = e3; sade[D_][B_] = e3;
            if (e3 < thrM) { atomicOr(&wloc[B_], 1u<<D_); atomicOr(&wloc[D_], 1u<<B_); }
            if (offd) {
                sade[A_][D_] = e1; sade[D_][A_] = e1;
                if (e1 < thrM) { atomicOr(&wloc[A_], 1u<<D_); atomicOr(&wloc[D_], 1u<<A_); }
                sade[B_][C_] = e2; sade[C_][B_] = e2;
                if (e2 < thrM) { atomicOr(&wloc[B_], 1u<<C_); atomicOr(&wloc[C_], 1u<<B_); }
            }
        }
    }
    __syncthreads();

    // ---- phase C: NMS pipeline, redundantly on EVERY wave (results in regs) ----
    // valid[] encoding detection (u8 bool / i32 / f32)
    bool fHit = (u0 == 0x3F800000u) || (u1 == 0x3F800000u);
    int nz0 = ((u0&0xFFu)!=0)+((u0&0xFF00u)!=0)+((u0&0xFF0000u)!=0)+((u0&0xFF000000u)!=0);
    int nz1 = ((u1&0xFFu)!=0)+((u1&0xFF00u)!=0)+((u1&0xFF0000u)!=0)+((u1&0xFF000000u)!=0);
    bool isF = __any(fHit), multi = __any(nz0 >= 2 || nz1 >= 2);
    int vflag;
    if (isF)        vflag = (((const float*)valid_raw)[blk] != 0.0f);
    else if (multi) vflag = (((const unsigned char*)valid_raw)[blk] != 0);
    else            vflag = (((const int*)valid_raw)[blk] != 0);

    unsigned wl = wloc[p];

    // greedy MTR scan: 5-level fmax reduce + ballot/ffs argmax (first-index tie-break)
    float carry = sc;
    int sel_0, sel_1, sel_2, sel_3, sel_4, sel_5;
#define GREEDY(SK) { \
    float vv = carry; \
    _Pragma("unroll") \
    for (int off = 16; off; off >>= 1) vv = fmaxf(vv, __shfl_xor(vv, off)); \
    unsigned long long mba = __ballot(carry == vv); \
    int bi = __ffsll((long long)mba) - 1; \
    SK = bi; \
    unsigned rbi = __shfl(wl, bi); \
    carry = (p == bi) ? -1.0f : (((rbi >> p) & 1u) ? carry*0.01f : carry); }
    GREEDY(sel_0) GREEDY(sel_1) GREEDY(sel_2) GREEDY(sel_3) GREEDY(sel_4) GREEDY(sel_5)
#undef GREEDY

    float q0 = __shfl(sc, sel_0), q1 = __shfl(sc, sel_1), q2 = __shfl(sc, sel_2);
    float q3 = __shfl(sc, sel_3), q4 = __shfl(sc, sel_4), q5 = __shfl(sc, sel_5);

    // MPA 6x6 within from LDS ADE matrix (lanes 0-14 of each wave, one pair each)
    int ii = (lane<5)?0 : (lane<9)?1 : (lane<12)?2 : (lane<14)?3 : 4;
    int jj = lane - ((ii==0)?-1 : (ii==1)?3 : (ii==2)?6 : (ii==3)?8 : 9);
    jj = (jj < 0) ? 0 : (jj > 5 ? 5 : jj);
    int pi = (ii==0)?sel_0:(ii==1)?sel_1:(ii==2)?sel_2:(ii==3)?sel_3:(ii==4)?sel_4:sel_5;
    int pj = (jj==0)?sel_0:(jj==1)?sel_1:(jj==2)?sel_2:(jj==3)?sel_3:(jj==4)?sel_4:sel_5;
    float ade15 = sade[pi][pj];
    bool within = (lane < 15) && (ade15 < thrQ);
    unsigned long long bal = __ballot(within);
#define B(i) ((unsigned)((bal >> (i)) & 1ull))
    unsigned w6_0 = (B(0)<<1)|(B(1)<<2)|(B(2)<<3)|(B(3)<<4)|(B(4)<<5);
    unsigned w6_1 = (B(0)<<0)|(B(5)<<2)|(B(6)<<3)|(B(7)<<4)|(B(8)<<5);
    unsigned w6_2 = (B(1)<<0)|(B(5)<<1)|(B(9)<<3)|(B(10)<<4)|(B(11)<<5);
    unsigned w6_3 = (B(2)<<0)|(B(6)<<1)|(B(9)<<2)|(B(12)<<4)|(B(13)<<5);
    unsigned w6_4 = (B(3)<<0)|(B(7)<<1)|(B(10)<<2)|(B(12)<<3)|(B(14)<<5);
    unsigned w6_5 = (B(4)<<0)|(B(8)<<1)|(B(11)<<2)|(B(13)<<3)|(B(14)<<4);
#undef B

    // stable ranks (argsort(-q), ties -> lower index)
#define GE(x,y) ((x) >= (y))
    bool a01=GE(q0,q1), a02=GE(q0,q2), a03=GE(q0,q3), a04=GE(q0,q4), a05=GE(q0,q5);
    bool a12=GE(q1,q2), a13=GE(q1,q3), a14=GE(q1,q4), a15=GE(q1,q5);
    bool a23=GE(q2,q3), a24=GE(q2,q4), a25=GE(q2,q5);
    bool a34=GE(q3,q4), a35=GE(q3,q5);
    bool a45=GE(q4,q5);
#undef GE
    int r0 = (!a01)+(!a02)+(!a03)+(!a04)+(!a05);
    int r1 = a01+(!a12)+(!a13)+(!a14)+(!a15);
    int r2 = a02+a12+(!a23)+(!a24)+(!a25);
    int r3 = a03+a13+a23+(!a34)+(!a35);
    int r4 = a04+a14+a24+a34+(!a45);
    int r5 = a05+a15+a25+a35+a45;

    // serial MPA scan, exact semantics, all-scalar
    const float sum6 = q0+q1+q2+q3+q4+q5;
    const float supv = 0.001f * sum6;
#define STEP(m) { \
    float ck = (r0==m)?q0:(r1==m)?q1:(r2==m)?q2:(r3==m)?q3:(r4==m)?q4:q5; \
    unsigned wk = (r0==m)?w6_0:(r1==m)?w6_1:(r2==m)?w6_2:(r3==m)?w6_3:(r4==m)?w6_4:w6_5; \
    bool sup = (((wk>>0)&1u)&&(q0>ck))||(((wk>>1)&1u)&&(q1>ck))||(((wk>>2)&1u)&&(q2>ck)) \
             ||(((wk>>3)&1u)&&(q3>ck))||(((wk>>4)&1u)&&(q4>ck))||(((wk>>5)&1u)&&(q5>ck)); \
    bool go = vflag && sup; \
    q0 = (go&&(r0==m))?supv:q0; q1 = (go&&(r1==m))?supv:q1; q2 = (go&&(r2==m))?supv:q2; \
    q3 = (go&&(r3==m))?supv:q3; q4 = (go&&(r4==m))?supv:q4; q5 = (go&&(r5==m))?supv:q5; }
    STEP(0) STEP(1) STEP(2) STEP(3) STEP(4) STEP(5)
#undef STEP

    // softmax(1.25*ln q) via fast log/exp (outputs have 1.82 absmax margin)
    float g0 = __logf(q0)*1.25f, g1 = __logf(q1)*1.25f, g2 = __logf(q2)*1.25f;
    float g3 = __logf(q3)*1.25f, g4 = __logf(q4)*1.25f, g5 = __logf(q5)*1.25f;
    float mx = fmaxf(fmaxf(fmaxf(g0,g1),fmaxf(g2,g3)),fmaxf(g4,g5));
    float e0 = __expf(g0-mx), e1 = __expf(g1-mx), e2 = __expf(g2-mx);
    float e3 = __expf(g3-mx), e4 = __expf(g4-mx), e5 = __expf(g5-mx);
    float es = e0+e1+e2+e3+e4+e5;

    if (tid < NK) {       // wave 0 only: scores output
        float fv = (lane==0)?e0:(lane==1)?e1:(lane==2)?e2:(lane==3)?e3:(lane==4)?e4:e5;
        out[BASE3 + (size_t)blk*NK + lane] = fv / es;
    }
    if (tid < NT)         // waves 0-1: valid output (vflag live per wave)
        out[BASE4 + (size_t)(s*NT + tid)*NA + a] = vflag ? 1.0f : 0.0f;

    // ---- phase D: traj outputs, NO barrier (sel in wave-uniform regs);
    //      gather float4 from global (L2-hot from phase A) ----
    if (tid < 3*NT) {
        int t = tid / 3, kp = tid - t*3;
        int k0 = kp*2;
        int s0sel = (kp==0)?sel_0:(kp==1)?sel_2:sel_4;
        int s1sel = (kp==0)?sel_1:(kp==1)?sel_3:sel_5;
        float4 v0 = tg4[(size_t)s0sel*NT + t];
        float4 v1 = tg4[(size_t)s1sel*NT + t];
        size_t ob = (((size_t)(s*NT + t)*NA + a)*NK + k0);   // float2-unit index (even)
        *(float4*)((float2*)out + ob) = make_float4(v0.x, v0.y, v1.x, v1.y);
        *(float2*)(out + BASE1 + ob) = make_float2(v0.z, v1.z);
        *(float2*)(out + BASE2 + ob) = make_float2(v0.w, v1.w);
    }
}

extern "C" void kernel_launch(void* const* d_in, const int* in_sizes, int n_in,
                              void* d_out, int out_size, void* d_ws, size_t ws_size,
                              hipStream_t stream) {
    const void*  valid  = d_in[0];
    const float* scores = (const float*)d_in[1];
    const float* trajs  = (const float*)d_in[2];
    const float* atype  = (const float*)d_in[3];
    k_fused<<<NAG, 512, 0, stream>>>(valid, scores, trajs, atype, (float*)d_out);
}